// Round 5
// baseline (58.263 us; speedup 1.0000x reference)
//
#include <hip/hip_runtime.h>

// Gather-mean: out[b][d] = mean_k table[idx[b][k]][d], K=32, D=128.
// Phase 1: per-row symmetric int8 quantize; per-row scale stored as u8 CODE
//   (code = ceil(rowmax*255/8); effective scale >= rowmax so no clipping).
//   Also zeroes the chunk work-counter for phase 2.
// Phase 2: PERSISTENT gather - exactly 256 blocks (1/CU, 1024 threads).
//   Full 100 KB code table staged in LDS once per block; 128-node chunks
//   claimed via global atomicAdd (chunk-exclusive output => deterministic).
//   Empirical law (R1-R4): gather time = line-requests / 113G/s when load-
//   balanced; R4's 391 mega-blocks hit the 391/512=76% imbalance factor.
//   Persistent + work-stealing restores balance: 3.2M reqs -> ~28-30 us.

#define K_NEIGH 32
#define D_FEAT 128
#define NODES_PC 128                       // nodes per chunk
#define MAX_N_LDS 102400                   // code-table LDS capacity (bytes)
#define DEQ (8.0f / (255.0f * 127.0f))     // code -> per-unit dequant scale

// ---------------- Phase 1: quantize fp32 rows -> u8 data + u8 scale code --
__global__ __launch_bounds__(256) void quantize_rows(
    const float* __restrict__ table,       // [N,128] fp32
    unsigned char* __restrict__ q8,        // [N,128] u8 (biased +128)
    unsigned char* __restrict__ codes,     // [N] u8 scale codes (4B-padded)
    unsigned int* __restrict__ counter,    // chunk work counter (zeroed here)
    int N)
{
    if (blockIdx.x == 0 && threadIdx.x == 0) *counter = 0u;

    const int lane = threadIdx.x & 63;
    const int wid  = threadIdx.x >> 6;
    const int row  = blockIdx.x * 4 + wid;
    if (row >= N) return;

    float2 v = ((const float2*)(table + (size_t)row * D_FEAT))[lane];
    float m = fmaxf(fabsf(v.x), fabsf(v.y));
    #pragma unroll
    for (int off = 32; off >= 1; off >>= 1)
        m = fmaxf(m, __shfl_xor(m, off, 64));

    int code = (int)ceilf(m * (255.0f / 8.0f));
    code = min(max(code, 1), 255);
    const float inv = 127.0f / ((float)code * (8.0f / 255.0f));  // |v|*inv <= 127

    float qx = fminf(fmaxf(rintf(v.x * inv), -127.f), 127.f);
    float qy = fminf(fmaxf(rintf(v.y * inv), -127.f), 127.f);
    unsigned int ux = (unsigned int)((int)qx + 128);
    unsigned int uy = (unsigned int)((int)qy + 128);
    ((unsigned short*)(q8 + (size_t)row * D_FEAT))[lane] =
        (unsigned short)(ux | (uy << 8));

    if (lane == 0) codes[row] = (unsigned char)code;
}

// ---------------- Phase 2: persistent gather + mean -----------------------
// 8 lanes per row (8 x 16 B). 1024 threads = 128 nodes per chunk.
__global__ __launch_bounds__(1024) void gather_mean_q8_pers(
    const int* __restrict__ neigh_idx,       // [B,32] int32
    const unsigned char* __restrict__ q8,    // [N,128] u8
    const unsigned char* __restrict__ codes, // [N] u8 (4B-padded)
    unsigned int* __restrict__ counter,      // chunk counter (pre-zeroed)
    float* __restrict__ out,                 // [B,128] fp32
    int B, int N, int nchunks)
{
    const int tid = threadIdx.x;

    __shared__ unsigned int s_code32[MAX_N_LDS / 4]; // 100 KB code table
    __shared__ int s_idx[NODES_PC * 33];             // padded, conflict-free
    __shared__ unsigned int s_chunk;

    // Stage the scale-code table once (coalesced stream).
    {
        const int nc32 = (N + 3) >> 2;
        const unsigned int* gsrc = (const unsigned int*)codes;
        for (int i = tid; i < nc32; i += 1024) s_code32[i] = gsrc[i];
    }

    const int g   = tid >> 3;            // node within chunk, 0..127
    const int sub = tid & 7;             // 16-byte slot within 128 B row
    const unsigned char* sc = (const unsigned char*)s_code32;
    const int total_idx = B * K_NEIGH;
    const float invK = 1.0f / (float)K_NEIGH;

    for (;;) {
        if (tid == 0) s_chunk = atomicAdd(counter, 1u);
        __syncthreads();                 // publishes s_chunk; guards s_idx reuse
        const unsigned int c = s_chunk;
        if (c >= (unsigned int)nchunks) break;     // uniform across block

        // Stage this chunk's 4096 indices.
        {
            const int base = (int)c * NODES_PC * K_NEIGH;
            #pragma unroll
            for (int t = 0; t < 4; ++t) {
                int li = tid + t * 1024;           // 0..4095
                int gi = base + li;
                s_idx[(li >> 5) * 33 + (li & 31)] =
                    (gi < total_idx) ? neigh_idx[gi] : 0;
            }
        }
        __syncthreads();

        const int node = (int)c * NODES_PC + g;
        if (node < B) {
            const int* my = &s_idx[g * 33];

            float acc[16];
            #pragma unroll
            for (int j = 0; j < 16; ++j) acc[j] = 0.f;
            float ssum = 0.f;

            #pragma unroll
            for (int k0 = 0; k0 < K_NEIGH; k0 += 8) {
                uint4 v[8];
                float s[8];
                #pragma unroll
                for (int j = 0; j < 8; ++j) {
                    int r = my[k0 + j];
                    v[j] = ((const uint4*)(q8 + (size_t)r * D_FEAT))[sub];
                    s[j] = (float)sc[r] * DEQ;     // LDS broadcast
                }
                #pragma unroll
                for (int j = 0; j < 8; ++j) {
                    const float sj = s[j];
                    ssum += sj;
                    unsigned int w;
                    w = v[j].x;
                    acc[0]  = fmaf((float)(w & 0xff),         sj, acc[0]);
                    acc[1]  = fmaf((float)((w >> 8)  & 0xff), sj, acc[1]);
                    acc[2]  = fmaf((float)((w >> 16) & 0xff), sj, acc[2]);
                    acc[3]  = fmaf((float)((w >> 24)       ), sj, acc[3]);
                    w = v[j].y;
                    acc[4]  = fmaf((float)(w & 0xff),         sj, acc[4]);
                    acc[5]  = fmaf((float)((w >> 8)  & 0xff), sj, acc[5]);
                    acc[6]  = fmaf((float)((w >> 16) & 0xff), sj, acc[6]);
                    acc[7]  = fmaf((float)((w >> 24)       ), sj, acc[7]);
                    w = v[j].z;
                    acc[8]  = fmaf((float)(w & 0xff),         sj, acc[8]);
                    acc[9]  = fmaf((float)((w >> 8)  & 0xff), sj, acc[9]);
                    acc[10] = fmaf((float)((w >> 16) & 0xff), sj, acc[10]);
                    acc[11] = fmaf((float)((w >> 24)       ), sj, acc[11]);
                    w = v[j].w;
                    acc[12] = fmaf((float)(w & 0xff),         sj, acc[12]);
                    acc[13] = fmaf((float)((w >> 8)  & 0xff), sj, acc[13]);
                    acc[14] = fmaf((float)((w >> 16) & 0xff), sj, acc[14]);
                    acc[15] = fmaf((float)((w >> 24)       ), sj, acc[15]);
                }
            }

            // elem = s*(u-128); out = (sum(s*u) - 128*sum(s)) / K
            const float bias = 128.f * ssum;
            float* orow = out + (size_t)node * D_FEAT + sub * 16;
            #pragma unroll
            for (int q = 0; q < 4; ++q) {
                float4 o;
                o.x = (acc[q * 4 + 0] - bias) * invK;
                o.y = (acc[q * 4 + 1] - bias) * invK;
                o.z = (acc[q * 4 + 2] - bias) * invK;
                o.w = (acc[q * 4 + 3] - bias) * invK;
                ((float4*)orow)[q] = o;
            }
        }
    }
}

// ---------------- Fallback: scales from global (N too big for LDS) --------
__global__ __launch_bounds__(256) void gather_mean_q8_glb(
    const int* __restrict__ neigh_idx,
    const unsigned char* __restrict__ q8,
    const unsigned char* __restrict__ codes,
    float* __restrict__ out, int B)
{
    const int tid = threadIdx.x;
    const int g   = tid >> 3;
    const int sub = tid & 7;
    const int node = blockIdx.x * 32 + g;

    __shared__ int s_idx[32 * 33];
    {
        const int base = blockIdx.x * 32 * K_NEIGH;
        const int total = B * K_NEIGH;
        #pragma unroll
        for (int t = 0; t < 4; ++t) {
            int li = tid + t * 256;
            int gi = base + li;
            s_idx[(li >> 5) * 33 + (li & 31)] = (gi < total) ? neigh_idx[gi] : 0;
        }
    }
    __syncthreads();
    if (node >= B) return;

    const int* my = &s_idx[g * 33];
    float acc[16];
    #pragma unroll
    for (int j = 0; j < 16; ++j) acc[j] = 0.f;
    float ssum = 0.f;

    #pragma unroll
    for (int k0 = 0; k0 < K_NEIGH; k0 += 8) {
        uint4 v[8];
        float s[8];
        #pragma unroll
        for (int j = 0; j < 8; ++j) {
            int r = my[k0 + j];
            v[j] = ((const uint4*)(q8 + (size_t)r * D_FEAT))[sub];
            s[j] = (float)codes[r] * DEQ;
        }
        #pragma unroll
        for (int j = 0; j < 8; ++j) {
            const float sj = s[j];
            ssum += sj;
            unsigned int w;
            w = v[j].x;
            acc[0]  = fmaf((float)(w & 0xff),         sj, acc[0]);
            acc[1]  = fmaf((float)((w >> 8)  & 0xff), sj, acc[1]);
            acc[2]  = fmaf((float)((w >> 16) & 0xff), sj, acc[2]);
            acc[3]  = fmaf((float)((w >> 24)       ), sj, acc[3]);
            w = v[j].y;
            acc[4]  = fmaf((float)(w & 0xff),         sj, acc[4]);
            acc[5]  = fmaf((float)((w >> 8)  & 0xff), sj, acc[5]);
            acc[6]  = fmaf((float)((w >> 16) & 0xff), sj, acc[6]);
            acc[7]  = fmaf((float)((w >> 24)       ), sj, acc[7]);
            w = v[j].z;
            acc[8]  = fmaf((float)(w & 0xff),         sj, acc[8]);
            acc[9]  = fmaf((float)((w >> 8)  & 0xff), sj, acc[9]);
            acc[10] = fmaf((float)((w >> 16) & 0xff), sj, acc[10]);
            acc[11] = fmaf((float)((w >> 24)       ), sj, acc[11]);
            w = v[j].w;
            acc[12] = fmaf((float)(w & 0xff),         sj, acc[12]);
            acc[13] = fmaf((float)((w >> 8)  & 0xff), sj, acc[13]);
            acc[14] = fmaf((float)((w >> 16) & 0xff), sj, acc[14]);
            acc[15] = fmaf((float)((w >> 24)       ), sj, acc[15]);
        }
    }

    const float bias = 128.f * ssum;
    const float invK = 1.0f / (float)K_NEIGH;
    float* orow = out + (size_t)node * D_FEAT + sub * 16;
    #pragma unroll
    for (int q = 0; q < 4; ++q) {
        float4 o;
        o.x = (acc[q * 4 + 0] - bias) * invK;
        o.y = (acc[q * 4 + 1] - bias) * invK;
        o.z = (acc[q * 4 + 2] - bias) * invK;
        o.w = (acc[q * 4 + 3] - bias) * invK;
        ((float4*)orow)[q] = o;
    }
}

// ---------------- Fallback (ws too small): fp32 gather --------------------
__global__ __launch_bounds__(256) void gather_mean_f32(
    const int* __restrict__ neigh_idx,
    const float* __restrict__ table,
    float* __restrict__ out, int B)
{
    const int tid = threadIdx.x;
    const int node_in_blk = tid >> 5;
    const int lane = tid & 31;
    const int node = blockIdx.x * 8 + node_in_blk;

    __shared__ int s_idx[8 * K_NEIGH];
    {
        long long gi = (long long)blockIdx.x * (8 * K_NEIGH) + tid;
        long long total = (long long)B * K_NEIGH;
        s_idx[tid] = (gi < total) ? neigh_idx[gi] : 0;
    }
    __syncthreads();
    if (node >= B) return;

    const int* my = &s_idx[node_in_blk * K_NEIGH];
    float4 acc0 = {0,0,0,0}, acc1 = {0,0,0,0};
    #pragma unroll
    for (int k = 0; k < K_NEIGH; k += 2) {
        int r0 = my[k], r1 = my[k+1];
        float4 v0 = ((const float4*)(table + (size_t)r0 * D_FEAT))[lane];
        float4 v1 = ((const float4*)(table + (size_t)r1 * D_FEAT))[lane];
        acc0.x+=v0.x; acc0.y+=v0.y; acc0.z+=v0.z; acc0.w+=v0.w;
        acc1.x+=v1.x; acc1.y+=v1.y; acc1.z+=v1.z; acc1.w+=v1.w;
    }
    const float s = 1.0f / (float)K_NEIGH;
    float4 res = {(acc0.x+acc1.x)*s, (acc0.y+acc1.y)*s,
                  (acc0.z+acc1.z)*s, (acc0.w+acc1.w)*s};
    ((float4*)(out + (size_t)node * D_FEAT))[lane] = res;
}

extern "C" void kernel_launch(void* const* d_in, const int* in_sizes, int n_in,
                              void* d_out, int out_size, void* d_ws, size_t ws_size,
                              hipStream_t stream) {
    const int* neigh_idx = (const int*)d_in[0];     // [B*32] int32
    const float* table   = (const float*)d_in[1];   // [N*128] fp32
    float* out           = (float*)d_out;           // [B*128] fp32

    const int B = in_sizes[0] / K_NEIGH;            // 50000
    const int N = in_sizes[1] / D_FEAT;             // 100000
    const size_t codes_bytes = ((size_t)N + 3) & ~(size_t)3;
    const size_t q8_bytes = (size_t)N * D_FEAT;
    // counter placed after codes, 64B-aligned
    const size_t ctr_off = (q8_bytes + codes_bytes + 63) & ~(size_t)63;
    const size_t need = ctr_off + 64;

    if (ws_size >= need) {
        unsigned char* q8 = (unsigned char*)d_ws;
        unsigned char* codes = q8 + q8_bytes;
        unsigned int* counter = (unsigned int*)((char*)d_ws + ctr_off);

        quantize_rows<<<(N + 3) / 4, 256, 0, stream>>>(table, q8, codes, counter, N);
        if (N <= MAX_N_LDS) {
            const int nchunks = (B + NODES_PC - 1) / NODES_PC;
            gather_mean_q8_pers<<<256, 1024, 0, stream>>>(
                neigh_idx, q8, codes, counter, out, B, N, nchunks);
        } else {
            gather_mean_q8_glb<<<(B + 31) / 32, 256, 0, stream>>>(
                neigh_idx, q8, codes, out, B);
        }
    } else {
        gather_mean_f32<<<(B + 7) / 8, 256, 0, stream>>>(neigh_idx, table, out, B);
    }
}

// Round 6
// 47.946 us; speedup vs baseline: 1.2152x; 1.2152x over previous
//
#include <hip/hip_runtime.h>

// Gather-mean: out[b][d] = mean_k table[idx[b][k]][d], K=32, D=128.
// Law (R1-R5): the random-gather line path saturates at ~7.25 TB/s of
// 64B-line traffic when occupancy is R3-like (256-thread blocks, many
// blocks/CU); R4/R5's single 1024-thread block/CU throttled it to 5.1.
// This round: int8 data (2 lines/row) + per-16-ROW-GROUP scale codes
// (6.25 KB table staged in LDS per block -> zero scale line traffic,
// ~12 KB LDS/block so 8 blocks/CU). Pipe bytes: 205 data + 9.8 staging
// + 6.4 idx = 221 MB -> ~30 us.

#define K_NEIGH 32
#define D_FEAT 128
#define GRP_SH 4                            // 16 rows per scale group
#define MAX_GROUPS 8192                     // LDS code capacity (bytes)
#define DEQ (8.0f / (255.0f * 127.0f))      // code -> per-unit dequant scale

// ---------------- Phase 1: quantize fp32 rows -> u8 + per-group code ------
// One wave per group of 16 rows (2048 floats, 32/lane). 4 waves/block.
__global__ __launch_bounds__(256) void quantize_groups(
    const float* __restrict__ table,        // [N,128] fp32
    unsigned int* __restrict__ q8,          // [N*128/4] u8 packed (bias +128)
    unsigned char* __restrict__ codes,      // [ceil(N/16)] u8 scale codes
    int N)
{
    const int lane = threadIdx.x & 63;
    const int wid  = threadIdx.x >> 6;
    const int grp  = blockIdx.x * 4 + wid;
    const long long total_f4 = (long long)N * (D_FEAT / 4);
    const long long base_f4 = (long long)grp * (16 * D_FEAT / 4);  // 512 f4/group
    if (base_f4 >= total_f4) return;

    const float4* in4 = (const float4*)table;
    float4 v[8];
    bool ok[8];
    float m = 0.f;
    #pragma unroll
    for (int t = 0; t < 8; ++t) {
        long long i = base_f4 + lane + 64 * t;
        ok[t] = (i < total_f4);
        v[t] = ok[t] ? in4[i] : make_float4(0.f, 0.f, 0.f, 0.f);
        m = fmaxf(m, fmaxf(fmaxf(fabsf(v[t].x), fabsf(v[t].y)),
                           fmaxf(fabsf(v[t].z), fabsf(v[t].w))));
    }
    #pragma unroll
    for (int off = 32; off >= 1; off >>= 1)
        m = fmaxf(m, __shfl_xor(m, off, 64));

    int code = (int)ceilf(m * (255.0f / 8.0f));
    code = min(max(code, 1), 255);
    const float inv = (127.0f * 255.0f / 8.0f) / (float)code;  // |v|*inv <= 127

    #pragma unroll
    for (int t = 0; t < 8; ++t) {
        if (!ok[t]) continue;
        int qx = (int)rintf(v[t].x * inv) + 128;
        int qy = (int)rintf(v[t].y * inv) + 128;
        int qz = (int)rintf(v[t].z * inv) + 128;
        int qw = (int)rintf(v[t].w * inv) + 128;
        unsigned int w = (unsigned int)qx | ((unsigned int)qy << 8) |
                         ((unsigned int)qz << 16) | ((unsigned int)qw << 24);
        q8[base_f4 + lane + 64 * t] = w;
    }
    if (lane == 0) codes[grp] = (unsigned char)code;
}

// ---------------- Phase 2: gather + mean, group codes in LDS --------------
// 8 lanes per row (8 x 16 B). 256 threads = 32 nodes/block. 8 blocks/CU.
__global__ __launch_bounds__(256) void gather_mean_q8g(
    const int* __restrict__ neigh_idx,        // [B,32] int32
    const unsigned char* __restrict__ q8,     // [N,128] u8
    const unsigned char* __restrict__ codes,  // [ngroups] u8 (4B-padded)
    float* __restrict__ out,                  // [B,128] fp32
    int B, int ngroups)
{
    const int tid = threadIdx.x;

    __shared__ unsigned int s_code32[MAX_GROUPS / 4];  // <= 8 KB
    __shared__ int s_idx[32 * 33];                     // padded, conflict-free

    {
        const int nc32 = (ngroups + 3) >> 2;
        const unsigned int* gsrc = (const unsigned int*)codes;
        for (int i = tid; i < nc32; i += 256) s_code32[i] = gsrc[i];
    }
    {
        const int base = blockIdx.x * 32 * K_NEIGH;
        const int total = B * K_NEIGH;
        #pragma unroll
        for (int t = 0; t < 4; ++t) {
            int li = tid + t * 256;                    // 0..1023
            int gi = base + li;
            s_idx[(li >> 5) * 33 + (li & 31)] = (gi < total) ? neigh_idx[gi] : 0;
        }
    }
    __syncthreads();

    const int g   = tid >> 3;            // node within block, 0..31
    const int sub = tid & 7;             // 16-byte slot within 128 B row
    const int node = blockIdx.x * 32 + g;
    if (node >= B) return;

    const int* my = &s_idx[g * 33];
    const unsigned char* sc = (const unsigned char*)s_code32;

    float acc[16];
    #pragma unroll
    for (int j = 0; j < 16; ++j) acc[j] = 0.f;
    float ssum = 0.f;

    #pragma unroll
    for (int k0 = 0; k0 < K_NEIGH; k0 += 8) {
        uint4 v[8];
        float s[8];
        #pragma unroll
        for (int j = 0; j < 8; ++j) {
            int r = my[k0 + j];
            v[j] = ((const uint4*)(q8 + (size_t)r * D_FEAT))[sub];
            s[j] = (float)sc[r >> GRP_SH] * DEQ;      // LDS broadcast
        }
        #pragma unroll
        for (int j = 0; j < 8; ++j) {
            const float sj = s[j];
            ssum += sj;
            unsigned int w;
            w = v[j].x;
            acc[0]  = fmaf((float)(w & 0xff),         sj, acc[0]);
            acc[1]  = fmaf((float)((w >> 8)  & 0xff), sj, acc[1]);
            acc[2]  = fmaf((float)((w >> 16) & 0xff), sj, acc[2]);
            acc[3]  = fmaf((float)((w >> 24)       ), sj, acc[3]);
            w = v[j].y;
            acc[4]  = fmaf((float)(w & 0xff),         sj, acc[4]);
            acc[5]  = fmaf((float)((w >> 8)  & 0xff), sj, acc[5]);
            acc[6]  = fmaf((float)((w >> 16) & 0xff), sj, acc[6]);
            acc[7]  = fmaf((float)((w >> 24)       ), sj, acc[7]);
            w = v[j].z;
            acc[8]  = fmaf((float)(w & 0xff),         sj, acc[8]);
            acc[9]  = fmaf((float)((w >> 8)  & 0xff), sj, acc[9]);
            acc[10] = fmaf((float)((w >> 16) & 0xff), sj, acc[10]);
            acc[11] = fmaf((float)((w >> 24)       ), sj, acc[11]);
            w = v[j].w;
            acc[12] = fmaf((float)(w & 0xff),         sj, acc[12]);
            acc[13] = fmaf((float)((w >> 8)  & 0xff), sj, acc[13]);
            acc[14] = fmaf((float)((w >> 16) & 0xff), sj, acc[14]);
            acc[15] = fmaf((float)((w >> 24)       ), sj, acc[15]);
        }
    }

    // elem = s*(u-128); out = (sum(s*u) - 128*sum(s)) / K
    const float bias = 128.f * ssum;
    const float invK = 1.0f / (float)K_NEIGH;
    float* orow = out + (size_t)node * D_FEAT + sub * 16;
    #pragma unroll
    for (int q = 0; q < 4; ++q) {
        float4 o;
        o.x = (acc[q * 4 + 0] - bias) * invK;
        o.y = (acc[q * 4 + 1] - bias) * invK;
        o.z = (acc[q * 4 + 2] - bias) * invK;
        o.w = (acc[q * 4 + 3] - bias) * invK;
        ((float4*)orow)[q] = o;
    }
}

// ---------------- Fallback: codes from global (N too big for LDS) ---------
__global__ __launch_bounds__(256) void gather_mean_q8g_glb(
    const int* __restrict__ neigh_idx,
    const unsigned char* __restrict__ q8,
    const unsigned char* __restrict__ codes,
    float* __restrict__ out, int B)
{
    const int tid = threadIdx.x;
    const int g   = tid >> 3;
    const int sub = tid & 7;
    const int node = blockIdx.x * 32 + g;

    __shared__ int s_idx[32 * 33];
    {
        const int base = blockIdx.x * 32 * K_NEIGH;
        const int total = B * K_NEIGH;
        #pragma unroll
        for (int t = 0; t < 4; ++t) {
            int li = tid + t * 256;
            int gi = base + li;
            s_idx[(li >> 5) * 33 + (li & 31)] = (gi < total) ? neigh_idx[gi] : 0;
        }
    }
    __syncthreads();
    if (node >= B) return;

    const int* my = &s_idx[g * 33];
    float acc[16];
    #pragma unroll
    for (int j = 0; j < 16; ++j) acc[j] = 0.f;
    float ssum = 0.f;

    #pragma unroll
    for (int k0 = 0; k0 < K_NEIGH; k0 += 8) {
        uint4 v[8];
        float s[8];
        #pragma unroll
        for (int j = 0; j < 8; ++j) {
            int r = my[k0 + j];
            v[j] = ((const uint4*)(q8 + (size_t)r * D_FEAT))[sub];
            s[j] = (float)codes[r >> GRP_SH] * DEQ;
        }
        #pragma unroll
        for (int j = 0; j < 8; ++j) {
            const float sj = s[j];
            ssum += sj;
            unsigned int w;
            w = v[j].x;
            acc[0]  = fmaf((float)(w & 0xff),         sj, acc[0]);
            acc[1]  = fmaf((float)((w >> 8)  & 0xff), sj, acc[1]);
            acc[2]  = fmaf((float)((w >> 16) & 0xff), sj, acc[2]);
            acc[3]  = fmaf((float)((w >> 24)       ), sj, acc[3]);
            w = v[j].y;
            acc[4]  = fmaf((float)(w & 0xff),         sj, acc[4]);
            acc[5]  = fmaf((float)((w >> 8)  & 0xff), sj, acc[5]);
            acc[6]  = fmaf((float)((w >> 16) & 0xff), sj, acc[6]);
            acc[7]  = fmaf((float)((w >> 24)       ), sj, acc[7]);
            w = v[j].z;
            acc[8]  = fmaf((float)(w & 0xff),         sj, acc[8]);
            acc[9]  = fmaf((float)((w >> 8)  & 0xff), sj, acc[9]);
            acc[10] = fmaf((float)((w >> 16) & 0xff), sj, acc[10]);
            acc[11] = fmaf((float)((w >> 24)       ), sj, acc[11]);
            w = v[j].w;
            acc[12] = fmaf((float)(w & 0xff),         sj, acc[12]);
            acc[13] = fmaf((float)((w >> 8)  & 0xff), sj, acc[13]);
            acc[14] = fmaf((float)((w >> 16) & 0xff), sj, acc[14]);
            acc[15] = fmaf((float)((w >> 24)       ), sj, acc[15]);
        }
    }

    const float bias = 128.f * ssum;
    const float invK = 1.0f / (float)K_NEIGH;
    float* orow = out + (size_t)node * D_FEAT + sub * 16;
    #pragma unroll
    for (int q = 0; q < 4; ++q) {
        float4 o;
        o.x = (acc[q * 4 + 0] - bias) * invK;
        o.y = (acc[q * 4 + 1] - bias) * invK;
        o.z = (acc[q * 4 + 2] - bias) * invK;
        o.w = (acc[q * 4 + 3] - bias) * invK;
        ((float4*)orow)[q] = o;
    }
}

// ---------------- Fallback (ws too small): fp32 gather --------------------
__global__ __launch_bounds__(256) void gather_mean_f32(
    const int* __restrict__ neigh_idx,
    const float* __restrict__ table,
    float* __restrict__ out, int B)
{
    const int tid = threadIdx.x;
    const int node_in_blk = tid >> 5;
    const int lane = tid & 31;
    const int node = blockIdx.x * 8 + node_in_blk;

    __shared__ int s_idx[8 * K_NEIGH];
    {
        long long gi = (long long)blockIdx.x * (8 * K_NEIGH) + tid;
        long long total = (long long)B * K_NEIGH;
        s_idx[tid] = (gi < total) ? neigh_idx[gi] : 0;
    }
    __syncthreads();
    if (node >= B) return;

    const int* my = &s_idx[node_in_blk * K_NEIGH];
    float4 acc0 = {0,0,0,0}, acc1 = {0,0,0,0};
    #pragma unroll
    for (int k = 0; k < K_NEIGH; k += 2) {
        int r0 = my[k], r1 = my[k+1];
        float4 v0 = ((const float4*)(table + (size_t)r0 * D_FEAT))[lane];
        float4 v1 = ((const float4*)(table + (size_t)r1 * D_FEAT))[lane];
        acc0.x+=v0.x; acc0.y+=v0.y; acc0.z+=v0.z; acc0.w+=v0.w;
        acc1.x+=v1.x; acc1.y+=v1.y; acc1.z+=v1.z; acc1.w+=v1.w;
    }
    const float s = 1.0f / (float)K_NEIGH;
    float4 res = {(acc0.x+acc1.x)*s, (acc0.y+acc1.y)*s,
                  (acc0.z+acc1.z)*s, (acc0.w+acc1.w)*s};
    ((float4*)(out + (size_t)node * D_FEAT))[lane] = res;
}

extern "C" void kernel_launch(void* const* d_in, const int* in_sizes, int n_in,
                              void* d_out, int out_size, void* d_ws, size_t ws_size,
                              hipStream_t stream) {
    const int* neigh_idx = (const int*)d_in[0];     // [B*32] int32
    const float* table   = (const float*)d_in[1];   // [N*128] fp32
    float* out           = (float*)d_out;           // [B*128] fp32

    const int B = in_sizes[0] / K_NEIGH;            // 50000
    const int N = in_sizes[1] / D_FEAT;             // 100000
    const int ngroups = (N + 15) >> GRP_SH;         // 6250
    const size_t q8_bytes = (size_t)N * D_FEAT;
    const size_t codes_bytes = ((size_t)ngroups + 3) & ~(size_t)3;
    const size_t need = q8_bytes + codes_bytes;

    if (ws_size >= need) {
        unsigned int* q8w = (unsigned int*)d_ws;
        unsigned char* codes = (unsigned char*)d_ws + q8_bytes;

        const int nblk_q = (ngroups + 3) / 4;       // 4 groups (waves) / block
        quantize_groups<<<nblk_q, 256, 0, stream>>>(table, q8w, codes, N);

        if (ngroups <= MAX_GROUPS) {
            gather_mean_q8g<<<(B + 31) / 32, 256, 0, stream>>>(
                neigh_idx, (const unsigned char*)d_ws, codes, out, B, ngroups);
        } else {
            gather_mean_q8g_glb<<<(B + 31) / 32, 256, 0, stream>>>(
                neigh_idx, (const unsigned char*)d_ws, codes, out, B);
        }
    } else {
        gather_mean_f32<<<(B + 7) / 8, 256, 0, stream>>>(neigh_idx, table, out, B);
    }
}

// Round 7
// 47.910 us; speedup vs baseline: 1.2161x; 1.0007x over previous
//
#include <hip/hip_runtime.h>

// Gather-mean: out[b][d] = mean_k table[idx[b][k]][d], K=32, D=128.
// Law (R1-R6): random-gather line path saturates at ~113G 64B-line
// requests/s with healthy occupancy (256-thr blocks, multiple blocks/CU).
// R6 structure kept: int8 data (2 lines/row), per-16-row-group u8 scale
// codes staged in LDS (6.25 KB), 32 nodes/block.
// R7 change: 2-deep software pipeline in the k-loop - two 8-row batches
// (uint4 data + scale) in flight, doubling per-wave outstanding requests
// to close the ~4us gap between R6 (~34us) and the 30.5us request floor.

#define K_NEIGH 32
#define D_FEAT 128
#define GRP_SH 4                            // 16 rows per scale group
#define MAX_GROUPS 8192                     // LDS code capacity (bytes)
#define DEQ (8.0f / (255.0f * 127.0f))      // code -> per-unit dequant scale

// ---------------- Phase 1: quantize fp32 rows -> u8 + per-group code ------
// One wave per group of 16 rows (2048 floats, 32/lane). 4 waves/block.
__global__ __launch_bounds__(256) void quantize_groups(
    const float* __restrict__ table,        // [N,128] fp32
    unsigned int* __restrict__ q8,          // [N*128/4] u8 packed (bias +128)
    unsigned char* __restrict__ codes,      // [ceil(N/16)] u8 scale codes
    int N)
{
    const int lane = threadIdx.x & 63;
    const int wid  = threadIdx.x >> 6;
    const int grp  = blockIdx.x * 4 + wid;
    const long long total_f4 = (long long)N * (D_FEAT / 4);
    const long long base_f4 = (long long)grp * (16 * D_FEAT / 4);  // 512 f4/group
    if (base_f4 >= total_f4) return;

    const float4* in4 = (const float4*)table;
    float4 v[8];
    bool ok[8];
    float m = 0.f;
    #pragma unroll
    for (int t = 0; t < 8; ++t) {
        long long i = base_f4 + lane + 64 * t;
        ok[t] = (i < total_f4);
        v[t] = ok[t] ? in4[i] : make_float4(0.f, 0.f, 0.f, 0.f);
        m = fmaxf(m, fmaxf(fmaxf(fabsf(v[t].x), fabsf(v[t].y)),
                           fmaxf(fabsf(v[t].z), fabsf(v[t].w))));
    }
    #pragma unroll
    for (int off = 32; off >= 1; off >>= 1)
        m = fmaxf(m, __shfl_xor(m, off, 64));

    int code = (int)ceilf(m * (255.0f / 8.0f));
    code = min(max(code, 1), 255);
    const float inv = (127.0f * 255.0f / 8.0f) / (float)code;  // |v|*inv <= 127

    #pragma unroll
    for (int t = 0; t < 8; ++t) {
        if (!ok[t]) continue;
        int qx = (int)rintf(v[t].x * inv) + 128;
        int qy = (int)rintf(v[t].y * inv) + 128;
        int qz = (int)rintf(v[t].z * inv) + 128;
        int qw = (int)rintf(v[t].w * inv) + 128;
        unsigned int w = (unsigned int)qx | ((unsigned int)qy << 8) |
                         ((unsigned int)qz << 16) | ((unsigned int)qw << 24);
        q8[base_f4 + lane + 64 * t] = w;
    }
    if (lane == 0) codes[grp] = (unsigned char)code;
}

// -------- decode helper: one uint4 (16 bytes) FMA'd into acc[16] ----------
__device__ __forceinline__ void decode16(const uint4& vv, float sj,
                                         float* acc, float& ssum)
{
    ssum += sj;
    unsigned int w;
    w = vv.x;
    acc[0]  = fmaf((float)(w & 0xff),         sj, acc[0]);
    acc[1]  = fmaf((float)((w >> 8)  & 0xff), sj, acc[1]);
    acc[2]  = fmaf((float)((w >> 16) & 0xff), sj, acc[2]);
    acc[3]  = fmaf((float)((w >> 24)       ), sj, acc[3]);
    w = vv.y;
    acc[4]  = fmaf((float)(w & 0xff),         sj, acc[4]);
    acc[5]  = fmaf((float)((w >> 8)  & 0xff), sj, acc[5]);
    acc[6]  = fmaf((float)((w >> 16) & 0xff), sj, acc[6]);
    acc[7]  = fmaf((float)((w >> 24)       ), sj, acc[7]);
    w = vv.z;
    acc[8]  = fmaf((float)(w & 0xff),         sj, acc[8]);
    acc[9]  = fmaf((float)((w >> 8)  & 0xff), sj, acc[9]);
    acc[10] = fmaf((float)((w >> 16) & 0xff), sj, acc[10]);
    acc[11] = fmaf((float)((w >> 24)       ), sj, acc[11]);
    w = vv.w;
    acc[12] = fmaf((float)(w & 0xff),         sj, acc[12]);
    acc[13] = fmaf((float)((w >> 8)  & 0xff), sj, acc[13]);
    acc[14] = fmaf((float)((w >> 16) & 0xff), sj, acc[14]);
    acc[15] = fmaf((float)((w >> 24)       ), sj, acc[15]);
}

// ---------------- Phase 2: gather + mean, 2-deep pipelined ----------------
// 8 lanes per row (8 x 16 B). 256 threads = 32 nodes/block.
__global__ __launch_bounds__(256) void gather_mean_q8g(
    const int* __restrict__ neigh_idx,        // [B,32] int32
    const unsigned char* __restrict__ q8,     // [N,128] u8
    const unsigned char* __restrict__ codes,  // [ngroups] u8 (4B-padded)
    float* __restrict__ out,                  // [B,128] fp32
    int B, int ngroups)
{
    const int tid = threadIdx.x;

    __shared__ unsigned int s_code32[MAX_GROUPS / 4];  // <= 8 KB
    __shared__ int s_idx[32 * 33];                     // padded, conflict-free

    {
        const int nc32 = (ngroups + 3) >> 2;
        const unsigned int* gsrc = (const unsigned int*)codes;
        for (int i = tid; i < nc32; i += 256) s_code32[i] = gsrc[i];
    }
    {
        const int base = blockIdx.x * 32 * K_NEIGH;
        const int total = B * K_NEIGH;
        #pragma unroll
        for (int t = 0; t < 4; ++t) {
            int li = tid + t * 256;                    // 0..1023
            int gi = base + li;
            s_idx[(li >> 5) * 33 + (li & 31)] = (gi < total) ? neigh_idx[gi] : 0;
        }
    }
    __syncthreads();

    const int g   = tid >> 3;            // node within block, 0..31
    const int sub = tid & 7;             // 16-byte slot within 128 B row
    const int node = blockIdx.x * 32 + g;
    if (node >= B) return;

    const int* my = &s_idx[g * 33];
    const unsigned char* sc = (const unsigned char*)s_code32;

    float acc[16];
    #pragma unroll
    for (int j = 0; j < 16; ++j) acc[j] = 0.f;
    float ssum = 0.f;

    uint4 va[8], vb[8];
    float sa[8], sb[8];

#define LOADB(V, S, K0)                                             \
    _Pragma("unroll")                                               \
    for (int j = 0; j < 8; ++j) {                                   \
        int r = my[(K0) + j];                                       \
        V[j] = ((const uint4*)(q8 + (size_t)r * D_FEAT))[sub];      \
        S[j] = (float)sc[r >> GRP_SH] * DEQ;                        \
    }
#define DECB(V, S)                                                  \
    _Pragma("unroll")                                               \
    for (int j = 0; j < 8; ++j) decode16(V[j], S[j], acc, ssum);

    // 2-deep pipeline over 4 batches of 8: L0 L1 D0 L2 D1 L3 D2 D3
    LOADB(va, sa, 0)
    LOADB(vb, sb, 8)
    DECB(va, sa)
    LOADB(va, sa, 16)
    DECB(vb, sb)
    LOADB(vb, sb, 24)
    DECB(va, sa)
    DECB(vb, sb)

#undef LOADB
#undef DECB

    // elem = s*(u-128); out = (sum(s*u) - 128*sum(s)) / K
    const float bias = 128.f * ssum;
    const float invK = 1.0f / (float)K_NEIGH;
    float* orow = out + (size_t)node * D_FEAT + sub * 16;
    #pragma unroll
    for (int q = 0; q < 4; ++q) {
        float4 o;
        o.x = (acc[q * 4 + 0] - bias) * invK;
        o.y = (acc[q * 4 + 1] - bias) * invK;
        o.z = (acc[q * 4 + 2] - bias) * invK;
        o.w = (acc[q * 4 + 3] - bias) * invK;
        ((float4*)orow)[q] = o;
    }
}

// ---------------- Fallback: codes from global (N too big for LDS) ---------
__global__ __launch_bounds__(256) void gather_mean_q8g_glb(
    const int* __restrict__ neigh_idx,
    const unsigned char* __restrict__ q8,
    const unsigned char* __restrict__ codes,
    float* __restrict__ out, int B)
{
    const int tid = threadIdx.x;
    const int g   = tid >> 3;
    const int sub = tid & 7;
    const int node = blockIdx.x * 32 + g;

    __shared__ int s_idx[32 * 33];
    {
        const int base = blockIdx.x * 32 * K_NEIGH;
        const int total = B * K_NEIGH;
        #pragma unroll
        for (int t = 0; t < 4; ++t) {
            int li = tid + t * 256;
            int gi = base + li;
            s_idx[(li >> 5) * 33 + (li & 31)] = (gi < total) ? neigh_idx[gi] : 0;
        }
    }
    __syncthreads();
    if (node >= B) return;

    const int* my = &s_idx[g * 33];
    float acc[16];
    #pragma unroll
    for (int j = 0; j < 16; ++j) acc[j] = 0.f;
    float ssum = 0.f;

    #pragma unroll
    for (int k0 = 0; k0 < K_NEIGH; k0 += 8) {
        uint4 v[8];
        float s[8];
        #pragma unroll
        for (int j = 0; j < 8; ++j) {
            int r = my[k0 + j];
            v[j] = ((const uint4*)(q8 + (size_t)r * D_FEAT))[sub];
            s[j] = (float)codes[r >> GRP_SH] * DEQ;
        }
        #pragma unroll
        for (int j = 0; j < 8; ++j) decode16(v[j], s[j], acc, ssum);
    }

    const float bias = 128.f * ssum;
    const float invK = 1.0f / (float)K_NEIGH;
    float* orow = out + (size_t)node * D_FEAT + sub * 16;
    #pragma unroll
    for (int q = 0; q < 4; ++q) {
        float4 o;
        o.x = (acc[q * 4 + 0] - bias) * invK;
        o.y = (acc[q * 4 + 1] - bias) * invK;
        o.z = (acc[q * 4 + 2] - bias) * invK;
        o.w = (acc[q * 4 + 3] - bias) * invK;
        ((float4*)orow)[q] = o;
    }
}

// ---------------- Fallback (ws too small): fp32 gather --------------------
__global__ __launch_bounds__(256) void gather_mean_f32(
    const int* __restrict__ neigh_idx,
    const float* __restrict__ table,
    float* __restrict__ out, int B)
{
    const int tid = threadIdx.x;
    const int node_in_blk = tid >> 5;
    const int lane = tid & 31;
    const int node = blockIdx.x * 8 + node_in_blk;

    __shared__ int s_idx[8 * K_NEIGH];
    {
        long long gi = (long long)blockIdx.x * (8 * K_NEIGH) + tid;
        long long total = (long long)B * K_NEIGH;
        s_idx[tid] = (gi < total) ? neigh_idx[gi] : 0;
    }
    __syncthreads();
    if (node >= B) return;

    const int* my = &s_idx[node_in_blk * K_NEIGH];
    float4 acc0 = {0,0,0,0}, acc1 = {0,0,0,0};
    #pragma unroll
    for (int k = 0; k < K_NEIGH; k += 2) {
        int r0 = my[k], r1 = my[k+1];
        float4 v0 = ((const float4*)(table + (size_t)r0 * D_FEAT))[lane];
        float4 v1 = ((const float4*)(table + (size_t)r1 * D_FEAT))[lane];
        acc0.x+=v0.x; acc0.y+=v0.y; acc0.z+=v0.z; acc0.w+=v0.w;
        acc1.x+=v1.x; acc1.y+=v1.y; acc1.z+=v1.z; acc1.w+=v1.w;
    }
    const float s = 1.0f / (float)K_NEIGH;
    float4 res = {(acc0.x+acc1.x)*s, (acc0.y+acc1.y)*s,
                  (acc0.z+acc1.z)*s, (acc0.w+acc1.w)*s};
    ((float4*)(out + (size_t)node * D_FEAT))[lane] = res;
}

extern "C" void kernel_launch(void* const* d_in, const int* in_sizes, int n_in,
                              void* d_out, int out_size, void* d_ws, size_t ws_size,
                              hipStream_t stream) {
    const int* neigh_idx = (const int*)d_in[0];     // [B*32] int32
    const float* table   = (const float*)d_in[1];   // [N*128] fp32
    float* out           = (float*)d_out;           // [B*128] fp32

    const int B = in_sizes[0] / K_NEIGH;            // 50000
    const int N = in_sizes[1] / D_FEAT;             // 100000
    const int ngroups = (N + 15) >> GRP_SH;         // 6250
    const size_t q8_bytes = (size_t)N * D_FEAT;
    const size_t codes_bytes = ((size_t)ngroups + 3) & ~(size_t)3;
    const size_t need = q8_bytes + codes_bytes;

    if (ws_size >= need) {
        unsigned int* q8w = (unsigned int*)d_ws;
        unsigned char* codes = (unsigned char*)d_ws + q8_bytes;

        const int nblk_q = (ngroups + 3) / 4;       // 4 groups (waves) / block
        quantize_groups<<<nblk_q, 256, 0, stream>>>(table, q8w, codes, N);

        if (ngroups <= MAX_GROUPS) {
            gather_mean_q8g<<<(B + 31) / 32, 256, 0, stream>>>(
                neigh_idx, (const unsigned char*)d_ws, codes, out, B, ngroups);
        } else {
            gather_mean_q8g_glb<<<(B + 31) / 32, 256, 0, stream>>>(
                neigh_idx, (const unsigned char*)d_ws, codes, out, B);
        }
    } else {
        gather_mean_f32<<<(B + 7) / 8, 256, 0, stream>>>(neigh_idx, table, out, B);
    }
}